// Round 17
// baseline (156.454 us; speedup 1.0000x reference)
//
#include <hip/hip_runtime.h>
#include <hip/hip_bf16.h>
#include <cmath>

// Decoder block: LN1 -> QKV(+V^T fused) -> split-j causal attention -> combine+LN2 -> MLP(GELU) -> residual
// B=2, T=2048, C=768, H=12, dh=64. All GEMMs bf16 MFMA 16x16x32, fp32 accumulate.
// r17 = r16 + MLP1 retiled to 128x64 / 2-wave / depth-2 (6 blocks/CU).

#define BB 2
#define TT 2048
#define CC 768
#define HH 12
#define DH 64
#define NROWS (BB*TT)   // 4096
#define NHEADS (BB*HH)  // 24

typedef __attribute__((ext_vector_type(8))) short bf16x8;
typedef __attribute__((ext_vector_type(4))) float f32x4;
typedef __attribute__((ext_vector_type(4))) unsigned short u16x4;

__device__ __forceinline__ unsigned short f2bf(float f){
  union { __hip_bfloat16 h; unsigned short u; } c;
  c.h = __float2bfloat16(f);
  return c.u;
}
__device__ __forceinline__ float bf2f(unsigned short u){
  union { unsigned int i; float f; } x; x.i = ((unsigned int)u) << 16; return x.f;
}
// XOR-swizzle for [rows][BK] bf16 LDS tiles. Returns ELEMENT index.
// BK=64: granule = (4kk+g)^(r&7). BK=32: granule = 4(r&1)+(g^((r>>1)&3)) ->
// all 8 granules per 16-lane group (r11: 0 conflicts measured).
template<int BK>
__device__ __forceinline__ int swzk(int r, int c){
  if constexpr (BK == 64) return (r << 6) + (c ^ ((r & 7) << 3));
  else                    return (r << 5) + (c ^ (((r >> 1) & 3) << 3));
}
template<int BK>
__device__ __forceinline__ int swzsrc(int r, int c){
  if constexpr (BK == 64) return c ^ ((r & 7) << 3);
  else                    return c ^ (((r >> 1) & 3) << 3);
}
__device__ __forceinline__ float wred_sum(float v){
  #pragma unroll
  for(int m = 1; m < 64; m <<= 1) v += __shfl_xor(v, m, 64);
  return v;
}
// tanh-form GELU (max |err| vs exact-erf gelu ~3e-4)
__device__ __forceinline__ float gelu_fast(float x){
  float x2 = x * x;
  float e = x * fmaf(x2, 0.044715f, 1.0f) * 2.30203136f;  // 2*c1*log2(e)
  float t = exp2f(e);
  return x - x / (t + 1.0f);
}
// async global->LDS, 16B per lane; dest = wave-uniform base + lane*16
__device__ __forceinline__ void gload_lds16(const void* g, void* l){
  __builtin_amdgcn_global_load_lds((const __attribute__((address_space(1))) void*)g,
                                   (__attribute__((address_space(3))) void*)l, 16, 0, 0);
}
// counted vmcnt wait (immediate must be a literal)
template<int N> __device__ __forceinline__ void waitcnt_vm(){
  if constexpr (N == 0)      asm volatile("s_waitcnt vmcnt(0)" ::: "memory");
  else if constexpr (N == 4) asm volatile("s_waitcnt vmcnt(4)" ::: "memory");
  else if constexpr (N == 6) asm volatile("s_waitcnt vmcnt(6)" ::: "memory");
  else if constexpr (N == 8) asm volatile("s_waitcnt vmcnt(8)" ::: "memory");
  else static_assert(N == 0 || N == 4 || N == 6 || N == 8, "unsupported vmcnt");
}

#define SCLOG2 (0.125f * 1.44269504f)   // score scale into log2 domain

// ---------------- fused prep: weight transposes + bias concat + LN1, ONE launch ----------------
// Vectorized: float4 loads (16B/lane), u16x4 bf16 stores along K (8B/lane).
__device__ __forceinline__ void tc_body(const float* __restrict__ in,
                                        unsigned short* __restrict__ out,
                                        int K, int N, int bx, int by,
                                        float (*tile)[33]){
  int n0 = bx * 32, k0 = by * 32;
  int t = threadIdx.x;
  int r = t >> 3, c4 = (t & 7) * 4;
  *(float4*)&tile[r][c4] = *(const float4*)&in[(size_t)(k0 + r) * N + n0 + c4];
  __syncthreads();
  u16x4 pk;
  #pragma unroll
  for(int j = 0; j < 4; j++) pk[j] = f2bf(tile[c4 + j][r]);
  *(u16x4*)&out[(size_t)(n0 + r) * K + k0 + c4] = pk;
}

__device__ __forceinline__ void ln_body(const float* __restrict__ in,
                                        const float* __restrict__ gm,
                                        const float* __restrict__ bt,
                                        unsigned short* __restrict__ out_b,
                                        int r){
  int t = threadIdx.x;
  const float* row = in + (size_t)r * CC;
  float v0 = row[t], v1 = row[t + 256], v2 = row[t + 512];
  float s = wred_sum(v0 + v1 + v2);
  __shared__ float red[4];
  if((t & 63) == 0) red[t >> 6] = s;
  __syncthreads();
  float mu = (red[0] + red[1] + red[2] + red[3]) * (1.0f / CC);
  float d0 = v0 - mu, d1 = v1 - mu, d2 = v2 - mu;
  float q = wred_sum(d0 * d0 + d1 * d1 + d2 * d2);
  __shared__ float red2[4];
  if((t & 63) == 0) red2[t >> 6] = q;
  __syncthreads();
  float var = (red2[0] + red2[1] + red2[2] + red2[3]) * (1.0f / CC);
  float rinv = rsqrtf(var + 1e-3f);
  float o0 = d0 * rinv * gm[t]       + bt[t];
  float o1 = d1 * rinv * gm[t + 256] + bt[t + 256];
  float o2 = d2 * rinv * gm[t + 512] + bt[t + 512];
  size_t base = (size_t)r * CC;
  out_b[base + t] = f2bf(o0); out_b[base + t + 256] = f2bf(o1); out_b[base + t + 512] = f2bf(o2);
}

__global__ __launch_bounds__(256) void prep_ln_kernel(const float* __restrict__ Wq,
                                                      const float* __restrict__ Wk,
                                                      const float* __restrict__ Wv,
                                                      const float* __restrict__ W1,
                                                      const float* __restrict__ W2,
                                                      const float* __restrict__ bq,
                                                      const float* __restrict__ bk,
                                                      const float* __restrict__ bv,
                                                      const float* __restrict__ x,
                                                      const float* __restrict__ ln1g,
                                                      const float* __restrict__ ln1b,
                                                      unsigned short* __restrict__ wqkv,
                                                      unsigned short* __restrict__ w1t,
                                                      unsigned short* __restrict__ w2t,
                                                      float* __restrict__ bqkv,
                                                      unsigned short* __restrict__ xlnb){
  __shared__ float tile[32][33];
  int o = blockIdx.x;
  if(o < 1728){                       // Wq/Wk/Wv: 3 x 24x24
    int z = o / 576, r = o % 576;
    const float* in = (z == 0) ? Wq : (z == 1) ? Wk : Wv;
    tc_body(in, wqkv + (size_t)z * CC * CC, CC, CC, r % 24, r / 24, tile);
  } else if(o < 4032){                // W1 (768,3072): 96x24
    int r = o - 1728;
    tc_body(W1, w1t, CC, 4 * CC, r % 96, r / 96, tile);
  } else if(o < 6336){                // W2 (3072,768): 24x96
    int r = o - 4032;
    tc_body(W2, w2t, 4 * CC, CC, r % 24, r / 24, tile);
  } else if(o < 6345){                // bias concat: 9 blocks
    int i = (o - 6336) * 256 + threadIdx.x;
    if(i < 3 * CC) bqkv[i] = (i < CC) ? bq[i] : (i < 2 * CC) ? bk[i - CC] : bv[i - 2 * CC];
  } else {                            // LN1: 4096 rows
    ln_body(x, ln1g, ln1b, xlnb, o - 6345);
  }
}

// ---------------- GEMM (generic): TILE x TILE, BK-deep, depth-3 counted-vmcnt ----
// XCD M-chunked remap (gridDim.y % 8 == 0). MODE 3: QKV+fused V^T; 2: +resid f32 (MLP2).
template<int MODE, int TILE, int BK>
__global__ __launch_bounds__(256) void gemm_bt(const unsigned short* __restrict__ A,
                                               const unsigned short* __restrict__ Bt,
                                               const float* __restrict__ bias,
                                               const float* __restrict__ resid,
                                               void* __restrict__ outp,
                                               unsigned short* __restrict__ vt,
                                               int M, int N, int K){
  constexpr int F = TILE / 32;
  constexpr int SEGS = TILE * BK / 512;
  constexpr int R = SEGS / 4;
  constexpr int NLD = 2 * R;
  constexpr int LPR = BK / 8;
  constexpr int RPS = 512 / BK;
  __shared__ unsigned short As[3][TILE * BK];
  __shared__ unsigned short Bs[3][TILE * BK];
  int nb = gridDim.x, mbL = gridDim.y >> 3;
  int flat = blockIdx.y * nb + blockIdx.x;
  int xcd = flat & 7, sfl = flat >> 3;
  int by = xcd * mbL + sfl / nb;
  int bx = sfl % nb;
  int m0 = by * TILE, n0 = bx * TILE;
  int t = threadIdx.x; int w = t >> 6; int l = t & 63;
  int g = l >> 4; int lc = l & 15;
  int wm = w >> 1, wn = w & 1;
  f32x4 zero4 = {0.f, 0.f, 0.f, 0.f};
  f32x4 acc[F][F];
  #pragma unroll
  for(int mi = 0; mi < F; mi++)
    #pragma unroll
    for(int ni = 0; ni < F; ni++) acc[mi][ni] = zero4;

  auto stage = [&](int ks, int cb){
    #pragma unroll
    for(int p = 0; p < R; p++){
      int sgi = w * R + p;
      int r = sgi * RPS + l / LPR;
      int c = (l % LPR) * 8;
      int csrc = swzsrc<BK>(r, c);
      gload_lds16(A  + (size_t)(m0 + r) * K + ks + csrc, &As[cb][sgi * 512]);
      gload_lds16(Bt + (size_t)(n0 + r) * K + ks + csrc, &Bs[cb][sgi * 512]);
    }
  };

  int nt = K / BK;
  stage(0, 0);
  if(nt > 1) stage(BK, 1);
  if(nt > 2) stage(2 * BK, 2);
  int cur = 0;
  for(int ti = 0; ti < nt; ti++){
    if(ti + 2 < nt)      waitcnt_vm<2 * NLD>();
    else if(ti + 1 < nt) waitcnt_vm<NLD>();
    else                 waitcnt_vm<0>();
    __builtin_amdgcn_s_barrier();
    #pragma unroll
    for(int kk = 0; kk < BK / 32; kk++){
      bf16x8 af[F], bfv[F];
      #pragma unroll
      for(int mi = 0; mi < F; mi++) af[mi]  = *(const bf16x8*)&As[cur][swzk<BK>(wm * (TILE / 2) + mi * 16 + lc, kk * 32 + g * 8)];
      #pragma unroll
      for(int ni = 0; ni < F; ni++) bfv[ni] = *(const bf16x8*)&Bs[cur][swzk<BK>(wn * (TILE / 2) + ni * 16 + lc, kk * 32 + g * 8)];
      #pragma unroll
      for(int mi = 0; mi < F; mi++)
        #pragma unroll
        for(int ni = 0; ni < F; ni++)
          acc[mi][ni] = __builtin_amdgcn_mfma_f32_16x16x32_bf16(af[mi], bfv[ni], acc[mi][ni], 0, 0, 0);
    }
    __builtin_amdgcn_s_barrier();
    if(ti + 3 < nt) stage((ti + 3) * BK, cur);
    cur = (cur == 2) ? 0 : cur + 1;
  }
  #pragma unroll
  for(int mi = 0; mi < F; mi++)
    #pragma unroll
    for(int ni = 0; ni < F; ni++){
      int col = n0 + wn * (TILE / 2) + ni * 16 + lc;
      float bvv = bias[col];
      if(MODE == 3 && col >= 2 * CC){
        int hh = (col - 2 * CC) >> 6, d = (col - 2 * CC) & 63;
        int rowb = m0 + wm * (TILE / 2) + mi * 16 + g * 4;
        int bb = rowb >> 11, tb = rowb & 2047;
        u16x4 pk;
        #pragma unroll
        for(int rr = 0; rr < 4; rr++) pk[rr] = f2bf(acc[mi][ni][rr] + bvv);
        *(u16x4*)&vt[(((size_t)bb * HH + hh) * DH + d) * TT + tb] = pk;
      } else {
        #pragma unroll
        for(int rr = 0; rr < 4; rr++){
          int row = m0 + wm * (TILE / 2) + mi * 16 + g * 4 + rr;
          float v = acc[mi][ni][rr] + bvv;
          size_t idx = (size_t)row * N + col;
          if(MODE == 1) v = gelu_fast(v);
          if(MODE == 2) ((float*)outp)[idx] = v + resid[idx];
          else          ((unsigned short*)outp)[idx] = f2bf(v);
        }
      }
    }
}

// ---------------- GEMM 128x64, 2-wave, BK=32, depth-2 (MLP1) ----------------
// Wave w owns rows w*64..+63, all 64 cols: acc 4x4, 8 ds_read : 16 MFMA per K-step.
// LDS 24KB -> 6 blocks/CU; grid 1536 -> 6 independent 2-wave pipelines per CU.
// NLD=6 loads/wave/stage (A 8 segs + B 4 segs over 2 waves). Conflict-free BK32 swizzle.
__global__ __launch_bounds__(128) void gemm_mn_gelu(const unsigned short* __restrict__ A,
                                                    const unsigned short* __restrict__ Bt,
                                                    const float* __restrict__ bias,
                                                    unsigned short* __restrict__ outp,
                                                    int M, int N, int K){
  __shared__ unsigned short As[2][128 * 32];
  __shared__ unsigned short Bs[2][64 * 32];
  int nb = gridDim.x, mbL = gridDim.y >> 3;
  int flat = blockIdx.y * nb + blockIdx.x;
  int xcd = flat & 7, sfl = flat >> 3;
  int by = xcd * mbL + sfl / nb;
  int bx = sfl % nb;
  int m0 = by * 128, n0 = bx * 64;
  int t = threadIdx.x; int w = t >> 6; int l = t & 63;
  int g = l >> 4, lc = l & 15;
  f32x4 zero4 = {0.f, 0.f, 0.f, 0.f};
  f32x4 acc[4][4];
  #pragma unroll
  for(int mi = 0; mi < 4; mi++)
    #pragma unroll
    for(int ni = 0; ni < 4; ni++) acc[mi][ni] = zero4;

  // stage: 12 segs of 512 elems (16 rows x 32 cols each; 4 lanes/row):
  // segs 0-7 = A rows seg*16.., segs 8-11 = B rows (seg-8)*16...
  int rsg = l >> 2, csg = (l & 3) * 8;
  auto stage = [&](int ks, int cb){
    #pragma unroll
    for(int p = 0; p < 6; p++){
      int sgi = w * 6 + p;
      if(sgi < 8){
        int r = sgi * 16 + rsg;
        int csrc = csg ^ (((r >> 1) & 3) << 3);
        gload_lds16(A + (size_t)(m0 + r) * K + ks + csrc, &As[cb][sgi * 512]);
      } else {
        int r = (sgi - 8) * 16 + rsg;
        int csrc = csg ^ (((r >> 1) & 3) << 3);
        gload_lds16(Bt + (size_t)(n0 + r) * K + ks + csrc, &Bs[cb][(sgi - 8) * 512]);
      }
    }
  };

  int nt = K >> 5;
  stage(0, 0);
  if(nt > 1) stage(32, 1);
  for(int ti = 0; ti < nt; ti++){
    if(ti + 1 < nt) waitcnt_vm<6>(); else waitcnt_vm<0>();
    __builtin_amdgcn_s_barrier();
    int cur = ti & 1;
    bf16x8 af[4], bfv[4];
    #pragma unroll
    for(int mi = 0; mi < 4; mi++) af[mi]  = *(const bf16x8*)&As[cur][swzk<32>(w * 64 + mi * 16 + lc, g * 8)];
    #pragma unroll
    for(int ni = 0; ni < 4; ni++) bfv[ni] = *(const bf16x8*)&Bs[cur][swzk<32>(ni * 16 + lc, g * 8)];
    #pragma unroll
    for(int mi = 0; mi < 4; mi++)
      #pragma unroll
      for(int ni = 0; ni < 4; ni++)
        acc[mi][ni] = __builtin_amdgcn_mfma_f32_16x16x32_bf16(af[mi], bfv[ni], acc[mi][ni], 0, 0, 0);
    __builtin_amdgcn_s_barrier();
    if(ti + 2 < nt) stage((ti + 2) * 32, cur);
  }
  #pragma unroll
  for(int mi = 0; mi < 4; mi++)
    #pragma unroll
    for(int ni = 0; ni < 4; ni++){
      int col = n0 + ni * 16 + lc;
      float bvv = bias[col];
      #pragma unroll
      for(int rr = 0; rr < 4; rr++){
        int row = m0 + w * 64 + mi * 16 + g * 4 + rr;
        outp[(size_t)row * N + col] = f2bf(gelu_fast(acc[mi][ni][rr] + bvv));
      }
    }
}

// ---------------- Flash attention v7: split-j x2, partial outputs ----
__global__ __launch_bounds__(256) void attn_kernel(const unsigned short* __restrict__ qkv,
                                                   const unsigned short* __restrict__ vt,
                                                   unsigned short* __restrict__ po,
                                                   float* __restrict__ pl,
                                                   float* __restrict__ pm){
  __shared__ unsigned short Aq[2][64 * 64];
  __shared__ unsigned short Vs[2][64 * 64];
  __shared__ unsigned short Ps[4][16 * 64];
  int o = blockIdx.x;
  int xcd = o & 7, qq = o >> 3;          // qq 0..191
  int head = xcd * 3 + (qq % 3);         // 0..23
  int r_ = qq / 3;                       // 0..63
  int bx = 31 - (r_ >> 1);               // 31..0 (heavy first)
  int sp = r_ & 1;
  int b = head / HH, h = head % HH;
  int t = threadIdx.x; int w = t >> 6; int l = t & 63;
  int g = l >> 4, lc = l & 15;
  int i0w = bx * 64 + w * 16;
  int irow = i0w + lc;
  unsigned short* pw = &Ps[w][0];

  int hh = (bx + 2) >> 1;                // split point
  int js0 = sp ? hh : 0;
  int js1 = sp ? (bx + 1) : hh;

  int rl = l >> 3;
  int csrc = ((l & 7) * 8) ^ (rl * 8);

  bf16x8 bk[2];
  #pragma unroll
  for(int kk = 0; kk < 2; kk++)
    bk[kk] = *(const bf16x8*)(qkv + (size_t)(b * TT + irow) * (3 * CC) + CC + h * DH + kk * 32 + g * 8);

  float m_ = 0.0f, lsum = 0.f;   // fixed ref point; only moves via rare path
  f32x4 zero4 = {0.f, 0.f, 0.f, 0.f};
  f32x4 o4[4];
  #pragma unroll
  for(int ds = 0; ds < 4; ds++) o4[ds] = zero4;

  auto stage = [&](int j0, int cb){
    #pragma unroll
    for(int p = 0; p < 2; p++){
      int sgi = w * 2 + p;
      int row = sgi * 8 + rl;
      gload_lds16(qkv + (size_t)(b * TT + j0 + row) * (3 * CC) + h * DH + csrc, &Aq[cb][sgi * 512]);
      gload_lds16(vt  + (size_t)(head * DH + row) * TT + j0 + csrc,             &Vs[cb][sgi * 512]);
    }
  };

  if(js0 < js1){
    stage(js0 * 64, js0 & 1);
    if(js0 + 1 < js1) stage((js0 + 1) * 64, (js0 + 1) & 1);

    for(int jt = js0; jt < js1; jt++){
      int j0 = jt * 64;
      int buf = jt & 1;
      if(jt + 1 < js1) waitcnt_vm<4>(); else waitcnt_vm<0>();
      __builtin_amdgcn_s_barrier();
      f32x4 s[4];
      __builtin_amdgcn_s_setprio(1);
      #pragma unroll
      for(int js = 0; js < 4; js++){
        s[js] = zero4;
        #pragma unroll
        for(int kk = 0; kk < 2; kk++){
          bf16x8 aq = *(const bf16x8*)&Aq[buf][swzk<64>(js * 16 + lc, kk * 32 + g * 8)];
          s[js] = __builtin_amdgcn_mfma_f32_16x16x32_bf16(aq, bk[kk], s[js], 0, 0, 0);
        }
      }
      __builtin_amdgcn_s_setprio(0);
      if(j0 + 63 > i0w){
        #pragma unroll
        for(int js = 0; js < 4; js++)
          #pragma unroll
          for(int rr = 0; rr < 4; rr++){
            int j = j0 + js * 16 + g * 4 + rr;
            if(j > irow) s[js][rr] = -1e30f;
          }
      }
      float nmSC = -m_ * SCLOG2;
      f32x4 p[4];
      float rsum = 0.f;
      #pragma unroll
      for(int js = 0; js < 4; js++)
        #pragma unroll
        for(int rr = 0; rr < 4; rr++){
          float pv = exp2f(fmaf(s[js][rr], SCLOG2, nmSC));
          p[js][rr] = pv;
          rsum += pv;
        }
      rsum += __shfl_xor(rsum, 16, 64);
      rsum += __shfl_xor(rsum, 32, 64);
      if(__builtin_expect(__any(!(rsum < 1e30f)), 0)){
        float mx = -1e30f;
        #pragma unroll
        for(int js = 0; js < 4; js++)
          #pragma unroll
          for(int rr = 0; rr < 4; rr++) mx = fmaxf(mx, s[js][rr]);
        mx = fmaxf(mx, __shfl_xor(mx, 16, 64));
        mx = fmaxf(mx, __shfl_xor(mx, 32, 64));
        float mn = fmaxf(m_, mx);
        float al = exp2f((m_ - mn) * SCLOG2);
        m_ = mn;
        lsum *= al;
        #pragma unroll
        for(int rr = 0; rr < 4; rr++){
          float alb = __shfl(al, g * 4 + rr, 64);
          #pragma unroll
          for(int ds = 0; ds < 4; ds++) o4[ds][rr] *= alb;
        }
        nmSC = -m_ * SCLOG2;
        rsum = 0.f;
        #pragma unroll
        for(int js = 0; js < 4; js++)
          #pragma unroll
          for(int rr = 0; rr < 4; rr++){
            float pv = exp2f(fmaf(s[js][rr], SCLOG2, nmSC));
            p[js][rr] = pv;
            rsum += pv;
          }
        rsum += __shfl_xor(rsum, 16, 64);
        rsum += __shfl_xor(rsum, 32, 64);
      }
      lsum += rsum;
      #pragma unroll
      for(int js = 0; js < 4; js++){
        u16x4 pk;
        #pragma unroll
        for(int rr = 0; rr < 4; rr++) pk[rr] = f2bf(p[js][rr]);
        *(u16x4*)&pw[swzk<64>(lc, js * 16 + g * 4)] = pk;
      }
      bf16x8 pa[2];
      #pragma unroll
      for(int kk = 0; kk < 2; kk++)
        pa[kk] = *(const bf16x8*)&pw[swzk<64>(lc, kk * 32 + g * 8)];
      __builtin_amdgcn_s_setprio(1);
      #pragma unroll
      for(int ds = 0; ds < 4; ds++)
        #pragma unroll
        for(int kk = 0; kk < 2; kk++){
          bf16x8 vb = *(const bf16x8*)&Vs[buf][swzk<64>(ds * 16 + lc, kk * 32 + g * 8)];
          o4[ds] = __builtin_amdgcn_mfma_f32_16x16x32_bf16(pa[kk], vb, o4[ds], 0, 0, 0);
        }
      __builtin_amdgcn_s_setprio(0);
      __builtin_amdgcn_s_barrier();
      if(jt + 2 < js1) stage((jt + 2) * 64, buf);
    }
  }
  size_t pobase = (size_t)sp * (NHEADS * TT * DH) + (size_t)head * TT * DH;
  #pragma unroll
  for(int rr = 0; rr < 4; rr++){
    int ig = i0w + g * 4 + rr;
    #pragma unroll
    for(int ds = 0; ds < 4; ds++)
      po[pobase + (size_t)ig * DH + ds * 16 + lc] = f2bf(o4[ds][rr]);
  }
  if(g == 0){
    size_t pidx = (size_t)sp * (NHEADS * TT) + (size_t)head * TT + i0w + lc;
    pl[pidx] = lsum;
    pm[pidx] = m_;
  }
}

// ---------------- combine partials + residual + LN2, one block per row ----------------
__global__ __launch_bounds__(256) void combine_ln2(const unsigned short* __restrict__ po,
                                                   const float* __restrict__ pl,
                                                   const float* __restrict__ pm,
                                                   const unsigned short* __restrict__ xlnb,
                                                   const float* __restrict__ gm,
                                                   const float* __restrict__ bt,
                                                   float* __restrict__ x1,
                                                   unsigned short* __restrict__ hln2){
  int r = blockIdx.x; int t = threadIdx.x;
  int b = r >> 11, i = r & 2047;
  float v[3];
  #pragma unroll
  for(int p = 0; p < 3; p++){
    int c = t + p * 256;
    int h = c >> 6, d = c & 63;
    size_t pidx = ((size_t)(b * HH + h)) * TT + i;
    float m0v = pm[pidx], m1v = pm[pidx + NHEADS * TT];
    float l0 = pl[pidx],  l1 = pl[pidx + NHEADS * TT];
    float M = fmaxf(m0v, m1v);
    float w0 = exp2f((m0v - M) * SCLOG2), w1 = exp2f((m1v - M) * SCLOG2);
    float p0 = bf2f(po[pidx * DH + d]);
    float p1 = bf2f(po[(size_t)NHEADS * TT * DH + pidx * DH + d]);
    float att = (p0 * w0 + p1 * w1) / (l0 * w0 + l1 * w1);
    v[p] = bf2f(xlnb[(size_t)r * CC + c]) + att;
  }
  float s = wred_sum(v[0] + v[1] + v[2]);
  __shared__ float red[4];
  if((t & 63) == 0) red[t >> 6] = s;
  __syncthreads();
  float mu = (red[0] + red[1] + red[2] + red[3]) * (1.0f / CC);
  float d0 = v[0] - mu, d1 = v[1] - mu, d2 = v[2] - mu;
  float q = wred_sum(d0 * d0 + d1 * d1 + d2 * d2);
  __shared__ float red2[4];
  if((t & 63) == 0) red2[t >> 6] = q;
  __syncthreads();
  float var = (red2[0] + red2[1] + red2[2] + red2[3]) * (1.0f / CC);
  float rinv = rsqrtf(var + 1e-3f);
  size_t base = (size_t)r * CC;
  x1[base + t] = v[0]; x1[base + t + 256] = v[1]; x1[base + t + 512] = v[2];
  hln2[base + t]       = f2bf(d0 * rinv * gm[t]       + bt[t]);
  hln2[base + t + 256] = f2bf(d1 * rinv * gm[t + 256] + bt[t + 256]);
  hln2[base + t + 512] = f2bf(d2 * rinv * gm[t + 512] + bt[t + 512]);
}

// ---------------- host launcher ----------------
extern "C" void kernel_launch(void* const* d_in, const int* in_sizes, int n_in,
                              void* d_out, int out_size, void* d_ws, size_t ws_size,
                              hipStream_t stream){
  const float* x    = (const float*)d_in[0];
  const float* ln1g = (const float*)d_in[1];
  const float* ln1b = (const float*)d_in[2];
  const float* Wq   = (const float*)d_in[3];
  const float* bq   = (const float*)d_in[4];
  const float* Wk   = (const float*)d_in[5];
  const float* bk   = (const float*)d_in[6];
  const float* Wv   = (const float*)d_in[7];
  const float* bv   = (const float*)d_in[8];
  const float* ln2g = (const float*)d_in[9];
  const float* ln2b = (const float*)d_in[10];
  const float* W1   = (const float*)d_in[11];
  const float* b1   = (const float*)d_in[12];
  const float* W2   = (const float*)d_in[13];
  const float* b2   = (const float*)d_in[14];

  char* ws = (char*)d_ws;
  unsigned short* po   = (unsigned short*)(ws + 0);         // 12582912 (2 splits x 24x2048x64 bf16)
  unsigned short* xlnb = (unsigned short*)(ws + 12582912);  // 6291456
  float*          x1   = (float*)(ws + 18874368);           // 12582912
  unsigned short* hln2 = (unsigned short*)(ws + 31457280);  // 6291456
  unsigned short* wqkv = (unsigned short*)(ws + 37748736);  // 3538944
  float*          bqkv = (float*)(ws + 41287680);           // 9216
  unsigned short* w1t  = (unsigned short*)(ws + 41296896);  // 4718592
  unsigned short* w2t  = (unsigned short*)(ws + 46015488);  // 4718592
  unsigned short* qkv  = (unsigned short*)(ws + 50734080);  // 18874368 (v third unused)
  unsigned short* vt   = (unsigned short*)(ws + 69608448);  // 6291456
  float*          pl   = (float*)(ws + 75899904);           // 393216
  float*          pm   = (float*)(ws + 76293120);           // 393216
  unsigned short* mlp1 = (unsigned short*)(ws + 50734080);  // aliases qkv+vt (dead by then)

  prep_ln_kernel<<<dim3(6345 + NROWS), 256, 0, stream>>>(Wq, Wk, Wv, W1, W2, bq, bk, bv,
                                                         x, ln1g, ln1b,
                                                         wqkv, w1t, w2t, bqkv, xlnb);

  gemm_bt<3, 128, 32><<<dim3(18, 32), 256, 0, stream>>>(xlnb, wqkv, bqkv, nullptr, qkv, vt, NROWS, 3 * CC, CC);

  attn_kernel<<<dim3(1536), 256, 0, stream>>>(qkv, vt, po, pl, pm);

  combine_ln2<<<dim3(NROWS), 256, 0, stream>>>(po, pl, pm, xlnb, ln2g, ln2b, x1, hln2);

  gemm_mn_gelu<<<dim3(48, 32), 128, 0, stream>>>(hln2, w1t, b1, mlp1, NROWS, 4 * CC, CC);

  gemm_bt<2, 64, 64><<<dim3(12, 64), 256, 0, stream>>>(mlp1, w2t, b2, x1, d_out, nullptr, NROWS, CC, 4 * CC);

  (void)in_sizes; (void)n_in; (void)out_size; (void)ws_size;
}

// Round 18
// 148.559 us; speedup vs baseline: 1.0531x; 1.0531x over previous
//
#include <hip/hip_runtime.h>
#include <hip/hip_bf16.h>
#include <cmath>

// Decoder block: LN1 -> QKV(+V^T fused) -> split-j causal attention -> combine+LN2 -> MLP(GELU) -> residual
// B=2, T=2048, C=768, H=12, dh=64. All GEMMs bf16 MFMA 16x16x32, fp32 accumulate.
// r18 = exact restore of r16/r14 (best measured: 149.0 us).

#define BB 2
#define TT 2048
#define CC 768
#define HH 12
#define DH 64
#define NROWS (BB*TT)   // 4096
#define NHEADS (BB*HH)  // 24

typedef __attribute__((ext_vector_type(8))) short bf16x8;
typedef __attribute__((ext_vector_type(4))) float f32x4;
typedef __attribute__((ext_vector_type(4))) unsigned short u16x4;

__device__ __forceinline__ unsigned short f2bf(float f){
  union { __hip_bfloat16 h; unsigned short u; } c;
  c.h = __float2bfloat16(f);
  return c.u;
}
__device__ __forceinline__ float bf2f(unsigned short u){
  union { unsigned int i; float f; } x; x.i = ((unsigned int)u) << 16; return x.f;
}
// XOR-swizzle for [rows][BK] bf16 LDS tiles. Returns ELEMENT index.
// BK=64: granule = (4kk+g)^(r&7). BK=32: granule = 4(r&1)+(g^((r>>1)&3)) ->
// all 8 granules per 16-lane group (r11: 0 conflicts measured).
template<int BK>
__device__ __forceinline__ int swzk(int r, int c){
  if constexpr (BK == 64) return (r << 6) + (c ^ ((r & 7) << 3));
  else                    return (r << 5) + (c ^ (((r >> 1) & 3) << 3));
}
template<int BK>
__device__ __forceinline__ int swzsrc(int r, int c){
  if constexpr (BK == 64) return c ^ ((r & 7) << 3);
  else                    return c ^ (((r >> 1) & 3) << 3);
}
__device__ __forceinline__ float wred_sum(float v){
  #pragma unroll
  for(int m = 1; m < 64; m <<= 1) v += __shfl_xor(v, m, 64);
  return v;
}
// tanh-form GELU (max |err| vs exact-erf gelu ~3e-4)
__device__ __forceinline__ float gelu_fast(float x){
  float x2 = x * x;
  float e = x * fmaf(x2, 0.044715f, 1.0f) * 2.30203136f;  // 2*c1*log2(e)
  float t = exp2f(e);
  return x - x / (t + 1.0f);
}
// async global->LDS, 16B per lane; dest = wave-uniform base + lane*16
__device__ __forceinline__ void gload_lds16(const void* g, void* l){
  __builtin_amdgcn_global_load_lds((const __attribute__((address_space(1))) void*)g,
                                   (__attribute__((address_space(3))) void*)l, 16, 0, 0);
}
// counted vmcnt wait (immediate must be a literal)
template<int N> __device__ __forceinline__ void waitcnt_vm(){
  if constexpr (N == 0)      asm volatile("s_waitcnt vmcnt(0)" ::: "memory");
  else if constexpr (N == 4) asm volatile("s_waitcnt vmcnt(4)" ::: "memory");
  else if constexpr (N == 8) asm volatile("s_waitcnt vmcnt(8)" ::: "memory");
  else static_assert(N == 0 || N == 4 || N == 8, "unsupported vmcnt");
}

#define SCLOG2 (0.125f * 1.44269504f)   // score scale into log2 domain

// ---------------- fused prep: weight transposes + bias concat + LN1, ONE launch ----------------
// Vectorized: float4 loads (16B/lane), u16x4 bf16 stores along K (8B/lane).
__device__ __forceinline__ void tc_body(const float* __restrict__ in,
                                        unsigned short* __restrict__ out,
                                        int K, int N, int bx, int by,
                                        float (*tile)[33]){
  int n0 = bx * 32, k0 = by * 32;
  int t = threadIdx.x;
  int r = t >> 3, c4 = (t & 7) * 4;
  *(float4*)&tile[r][c4] = *(const float4*)&in[(size_t)(k0 + r) * N + n0 + c4];
  __syncthreads();
  u16x4 pk;
  #pragma unroll
  for(int j = 0; j < 4; j++) pk[j] = f2bf(tile[c4 + j][r]);
  *(u16x4*)&out[(size_t)(n0 + r) * K + k0 + c4] = pk;
}

__device__ __forceinline__ void ln_body(const float* __restrict__ in,
                                        const float* __restrict__ gm,
                                        const float* __restrict__ bt,
                                        unsigned short* __restrict__ out_b,
                                        int r){
  int t = threadIdx.x;
  const float* row = in + (size_t)r * CC;
  float v0 = row[t], v1 = row[t + 256], v2 = row[t + 512];
  float s = wred_sum(v0 + v1 + v2);
  __shared__ float red[4];
  if((t & 63) == 0) red[t >> 6] = s;
  __syncthreads();
  float mu = (red[0] + red[1] + red[2] + red[3]) * (1.0f / CC);
  float d0 = v0 - mu, d1 = v1 - mu, d2 = v2 - mu;
  float q = wred_sum(d0 * d0 + d1 * d1 + d2 * d2);
  __shared__ float red2[4];
  if((t & 63) == 0) red2[t >> 6] = q;
  __syncthreads();
  float var = (red2[0] + red2[1] + red2[2] + red2[3]) * (1.0f / CC);
  float rinv = rsqrtf(var + 1e-3f);
  float o0 = d0 * rinv * gm[t]       + bt[t];
  float o1 = d1 * rinv * gm[t + 256] + bt[t + 256];
  float o2 = d2 * rinv * gm[t + 512] + bt[t + 512];
  size_t base = (size_t)r * CC;
  out_b[base + t] = f2bf(o0); out_b[base + t + 256] = f2bf(o1); out_b[base + t + 512] = f2bf(o2);
}

__global__ __launch_bounds__(256) void prep_ln_kernel(const float* __restrict__ Wq,
                                                      const float* __restrict__ Wk,
                                                      const float* __restrict__ Wv,
                                                      const float* __restrict__ W1,
                                                      const float* __restrict__ W2,
                                                      const float* __restrict__ bq,
                                                      const float* __restrict__ bk,
                                                      const float* __restrict__ bv,
                                                      const float* __restrict__ x,
                                                      const float* __restrict__ ln1g,
                                                      const float* __restrict__ ln1b,
                                                      unsigned short* __restrict__ wqkv,
                                                      unsigned short* __restrict__ w1t,
                                                      unsigned short* __restrict__ w2t,
                                                      float* __restrict__ bqkv,
                                                      unsigned short* __restrict__ xlnb){
  __shared__ float tile[32][33];
  int o = blockIdx.x;
  if(o < 1728){                       // Wq/Wk/Wv: 3 x 24x24
    int z = o / 576, r = o % 576;
    const float* in = (z == 0) ? Wq : (z == 1) ? Wk : Wv;
    tc_body(in, wqkv + (size_t)z * CC * CC, CC, CC, r % 24, r / 24, tile);
  } else if(o < 4032){                // W1 (768,3072): 96x24
    int r = o - 1728;
    tc_body(W1, w1t, CC, 4 * CC, r % 96, r / 96, tile);
  } else if(o < 6336){                // W2 (3072,768): 24x96
    int r = o - 4032;
    tc_body(W2, w2t, 4 * CC, CC, r % 24, r / 24, tile);
  } else if(o < 6345){                // bias concat: 9 blocks
    int i = (o - 6336) * 256 + threadIdx.x;
    if(i < 3 * CC) bqkv[i] = (i < CC) ? bq[i] : (i < 2 * CC) ? bk[i - CC] : bv[i - 2 * CC];
  } else {                            // LN1: 4096 rows
    ln_body(x, ln1g, ln1b, xlnb, o - 6345);
  }
}

// ---------------- GEMM (generic): TILE x TILE, BK-deep, depth-3 counted-vmcnt ----
// XCD M-chunked remap (gridDim.y % 8 == 0): each XCD owns gridDim.y/8 consecutive
// M-panels (A-panel set L2-resident per XCD) while B sweeps -> kills panel thrash.
// MODE 3: QKV with fused V^T; 1: +bias GELU bf16 (MLP1); 2: +bias +resid f32 (MLP2).
template<int MODE, int TILE, int BK>
__global__ __launch_bounds__(256) void gemm_bt(const unsigned short* __restrict__ A,
                                               const unsigned short* __restrict__ Bt,
                                               const float* __restrict__ bias,
                                               const float* __restrict__ resid,
                                               void* __restrict__ outp,
                                               unsigned short* __restrict__ vt,
                                               int M, int N, int K){
  constexpr int F = TILE / 32;
  constexpr int SEGS = TILE * BK / 512;
  constexpr int R = SEGS / 4;
  constexpr int NLD = 2 * R;
  constexpr int LPR = BK / 8;
  constexpr int RPS = 512 / BK;
  __shared__ unsigned short As[3][TILE * BK];
  __shared__ unsigned short Bs[3][TILE * BK];
  // XCD M-chunked bijective remap
  int nb = gridDim.x, mbL = gridDim.y >> 3;
  int flat = blockIdx.y * nb + blockIdx.x;
  int xcd = flat & 7, sfl = flat >> 3;
  int by = xcd * mbL + sfl / nb;
  int bx = sfl % nb;
  int m0 = by * TILE, n0 = bx * TILE;
  int t = threadIdx.x; int w = t >> 6; int l = t & 63;
  int g = l >> 4; int lc = l & 15;
  int wm = w >> 1, wn = w & 1;
  f32x4 zero4 = {0.f, 0.f, 0.f, 0.f};
  f32x4 acc[F][F];
  #pragma unroll
  for(int mi = 0; mi < F; mi++)
    #pragma unroll
    for(int ni = 0; ni < F; ni++) acc[mi][ni] = zero4;

  auto stage = [&](int ks, int cb){
    #pragma unroll
    for(int p = 0; p < R; p++){
      int sgi = w * R + p;
      int r = sgi * RPS + l / LPR;
      int c = (l % LPR) * 8;
      int csrc = swzsrc<BK>(r, c);
      gload_lds16(A  + (size_t)(m0 + r) * K + ks + csrc, &As[cb][sgi * 512]);
      gload_lds16(Bt + (size_t)(n0 + r) * K + ks + csrc, &Bs[cb][sgi * 512]);
    }
  };

  int nt = K / BK;
  stage(0, 0);
  if(nt > 1) stage(BK, 1);
  if(nt > 2) stage(2 * BK, 2);
  int cur = 0;
  for(int ti = 0; ti < nt; ti++){
    if(ti + 2 < nt)      waitcnt_vm<2 * NLD>();
    else if(ti + 1 < nt) waitcnt_vm<NLD>();
    else                 waitcnt_vm<0>();
    __builtin_amdgcn_s_barrier();
    #pragma unroll
    for(int kk = 0; kk < BK / 32; kk++){
      bf16x8 af[F], bfv[F];
      #pragma unroll
      for(int mi = 0; mi < F; mi++) af[mi]  = *(const bf16x8*)&As[cur][swzk<BK>(wm * (TILE / 2) + mi * 16 + lc, kk * 32 + g * 8)];
      #pragma unroll
      for(int ni = 0; ni < F; ni++) bfv[ni] = *(const bf16x8*)&Bs[cur][swzk<BK>(wn * (TILE / 2) + ni * 16 + lc, kk * 32 + g * 8)];
      #pragma unroll
      for(int mi = 0; mi < F; mi++)
        #pragma unroll
        for(int ni = 0; ni < F; ni++)
          acc[mi][ni] = __builtin_amdgcn_mfma_f32_16x16x32_bf16(af[mi], bfv[ni], acc[mi][ni], 0, 0, 0);
    }
    __builtin_amdgcn_s_barrier();
    if(ti + 3 < nt) stage((ti + 3) * BK, cur);
    cur = (cur == 2) ? 0 : cur + 1;
  }
  #pragma unroll
  for(int mi = 0; mi < F; mi++)
    #pragma unroll
    for(int ni = 0; ni < F; ni++){
      int col = n0 + wn * (TILE / 2) + ni * 16 + lc;
      float bvv = bias[col];
      if(MODE == 3 && col >= 2 * CC){
        int hh = (col - 2 * CC) >> 6, d = (col - 2 * CC) & 63;
        int rowb = m0 + wm * (TILE / 2) + mi * 16 + g * 4;
        int bb = rowb >> 11, tb = rowb & 2047;
        u16x4 pk;
        #pragma unroll
        for(int rr = 0; rr < 4; rr++) pk[rr] = f2bf(acc[mi][ni][rr] + bvv);
        *(u16x4*)&vt[(((size_t)bb * HH + hh) * DH + d) * TT + tb] = pk;
      } else {
        #pragma unroll
        for(int rr = 0; rr < 4; rr++){
          int row = m0 + wm * (TILE / 2) + mi * 16 + g * 4 + rr;
          float v = acc[mi][ni][rr] + bvv;
          size_t idx = (size_t)row * N + col;
          if(MODE == 1) v = gelu_fast(v);
          if(MODE == 2) ((float*)outp)[idx] = v + resid[idx];
          else          ((unsigned short*)outp)[idx] = f2bf(v);
        }
      }
    }
}

// ---------------- Flash attention v7: split-j x2, partial outputs ----
__global__ __launch_bounds__(256) void attn_kernel(const unsigned short* __restrict__ qkv,
                                                   const unsigned short* __restrict__ vt,
                                                   unsigned short* __restrict__ po,
                                                   float* __restrict__ pl,
                                                   float* __restrict__ pm){
  __shared__ unsigned short Aq[2][64 * 64];
  __shared__ unsigned short Vs[2][64 * 64];
  __shared__ unsigned short Ps[4][16 * 64];
  int o = blockIdx.x;
  int xcd = o & 7, qq = o >> 3;          // qq 0..191
  int head = xcd * 3 + (qq % 3);         // 0..23
  int r_ = qq / 3;                       // 0..63
  int bx = 31 - (r_ >> 1);               // 31..0 (heavy first)
  int sp = r_ & 1;
  int b = head / HH, h = head % HH;
  int t = threadIdx.x; int w = t >> 6; int l = t & 63;
  int g = l >> 4, lc = l & 15;
  int i0w = bx * 64 + w * 16;
  int irow = i0w + lc;
  unsigned short* pw = &Ps[w][0];

  int hh = (bx + 2) >> 1;                // split point
  int js0 = sp ? hh : 0;
  int js1 = sp ? (bx + 1) : hh;

  int rl = l >> 3;
  int csrc = ((l & 7) * 8) ^ (rl * 8);

  bf16x8 bk[2];
  #pragma unroll
  for(int kk = 0; kk < 2; kk++)
    bk[kk] = *(const bf16x8*)(qkv + (size_t)(b * TT + irow) * (3 * CC) + CC + h * DH + kk * 32 + g * 8);

  float m_ = 0.0f, lsum = 0.f;   // fixed ref point; only moves via rare path
  f32x4 zero4 = {0.f, 0.f, 0.f, 0.f};
  f32x4 o4[4];
  #pragma unroll
  for(int ds = 0; ds < 4; ds++) o4[ds] = zero4;

  auto stage = [&](int j0, int cb){
    #pragma unroll
    for(int p = 0; p < 2; p++){
      int sgi = w * 2 + p;
      int row = sgi * 8 + rl;
      gload_lds16(qkv + (size_t)(b * TT + j0 + row) * (3 * CC) + h * DH + csrc, &Aq[cb][sgi * 512]);
      gload_lds16(vt  + (size_t)(head * DH + row) * TT + j0 + csrc,             &Vs[cb][sgi * 512]);
    }
  };

  if(js0 < js1){
    stage(js0 * 64, js0 & 1);
    if(js0 + 1 < js1) stage((js0 + 1) * 64, (js0 + 1) & 1);

    for(int jt = js0; jt < js1; jt++){
      int j0 = jt * 64;
      int buf = jt & 1;
      if(jt + 1 < js1) waitcnt_vm<4>(); else waitcnt_vm<0>();
      __builtin_amdgcn_s_barrier();
      f32x4 s[4];
      __builtin_amdgcn_s_setprio(1);
      #pragma unroll
      for(int js = 0; js < 4; js++){
        s[js] = zero4;
        #pragma unroll
        for(int kk = 0; kk < 2; kk++){
          bf16x8 aq = *(const bf16x8*)&Aq[buf][swzk<64>(js * 16 + lc, kk * 32 + g * 8)];
          s[js] = __builtin_amdgcn_mfma_f32_16x16x32_bf16(aq, bk[kk], s[js], 0, 0, 0);
        }
      }
      __builtin_amdgcn_s_setprio(0);
      if(j0 + 63 > i0w){
        #pragma unroll
        for(int js = 0; js < 4; js++)
          #pragma unroll
          for(int rr = 0; rr < 4; rr++){
            int j = j0 + js * 16 + g * 4 + rr;
            if(j > irow) s[js][rr] = -1e30f;
          }
      }
      float nmSC = -m_ * SCLOG2;
      f32x4 p[4];
      float rsum = 0.f;
      #pragma unroll
      for(int js = 0; js < 4; js++)
        #pragma unroll
        for(int rr = 0; rr < 4; rr++){
          float pv = exp2f(fmaf(s[js][rr], SCLOG2, nmSC));
          p[js][rr] = pv;
          rsum += pv;
        }
      rsum += __shfl_xor(rsum, 16, 64);
      rsum += __shfl_xor(rsum, 32, 64);
      if(__builtin_expect(__any(!(rsum < 1e30f)), 0)){
        float mx = -1e30f;
        #pragma unroll
        for(int js = 0; js < 4; js++)
          #pragma unroll
          for(int rr = 0; rr < 4; rr++) mx = fmaxf(mx, s[js][rr]);
        mx = fmaxf(mx, __shfl_xor(mx, 16, 64));
        mx = fmaxf(mx, __shfl_xor(mx, 32, 64));
        float mn = fmaxf(m_, mx);
        float al = exp2f((m_ - mn) * SCLOG2);
        m_ = mn;
        lsum *= al;
        #pragma unroll
        for(int rr = 0; rr < 4; rr++){
          float alb = __shfl(al, g * 4 + rr, 64);
          #pragma unroll
          for(int ds = 0; ds < 4; ds++) o4[ds][rr] *= alb;
        }
        nmSC = -m_ * SCLOG2;
        rsum = 0.f;
        #pragma unroll
        for(int js = 0; js < 4; js++)
          #pragma unroll
          for(int rr = 0; rr < 4; rr++){
            float pv = exp2f(fmaf(s[js][rr], SCLOG2, nmSC));
            p[js][rr] = pv;
            rsum += pv;
          }
        rsum += __shfl_xor(rsum, 16, 64);
        rsum += __shfl_xor(rsum, 32, 64);
      }
      lsum += rsum;
      #pragma unroll
      for(int js = 0; js < 4; js++){
        u16x4 pk;
        #pragma unroll
        for(int rr = 0; rr < 4; rr++) pk[rr] = f2bf(p[js][rr]);
        *(u16x4*)&pw[swzk<64>(lc, js * 16 + g * 4)] = pk;
      }
      bf16x8 pa[2];
      #pragma unroll
      for(int kk = 0; kk < 2; kk++)
        pa[kk] = *(const bf16x8*)&pw[swzk<64>(lc, kk * 32 + g * 8)];
      __builtin_amdgcn_s_setprio(1);
      #pragma unroll
      for(int ds = 0; ds < 4; ds++)
        #pragma unroll
        for(int kk = 0; kk < 2; kk++){
          bf16x8 vb = *(const bf16x8*)&Vs[buf][swzk<64>(ds * 16 + lc, kk * 32 + g * 8)];
          o4[ds] = __builtin_amdgcn_mfma_f32_16x16x32_bf16(pa[kk], vb, o4[ds], 0, 0, 0);
        }
      __builtin_amdgcn_s_setprio(0);
      __builtin_amdgcn_s_barrier();
      if(jt + 2 < js1) stage((jt + 2) * 64, buf);
    }
  }
  size_t pobase = (size_t)sp * (NHEADS * TT * DH) + (size_t)head * TT * DH;
  #pragma unroll
  for(int rr = 0; rr < 4; rr++){
    int ig = i0w + g * 4 + rr;
    #pragma unroll
    for(int ds = 0; ds < 4; ds++)
      po[pobase + (size_t)ig * DH + ds * 16 + lc] = f2bf(o4[ds][rr]);
  }
  if(g == 0){
    size_t pidx = (size_t)sp * (NHEADS * TT) + (size_t)head * TT + i0w + lc;
    pl[pidx] = lsum;
    pm[pidx] = m_;
  }
}

// ---------------- combine partials + residual + LN2, one block per row ----------------
__global__ __launch_bounds__(256) void combine_ln2(const unsigned short* __restrict__ po,
                                                   const float* __restrict__ pl,
                                                   const float* __restrict__ pm,
                                                   const unsigned short* __restrict__ xlnb,
                                                   const float* __restrict__ gm,
                                                   const float* __restrict__ bt,
                                                   float* __restrict__ x1,
                                                   unsigned short* __restrict__ hln2){
  int r = blockIdx.x; int t = threadIdx.x;
  int b = r >> 11, i = r & 2047;
  float v[3];
  #pragma unroll
  for(int p = 0; p < 3; p++){
    int c = t + p * 256;
    int h = c >> 6, d = c & 63;
    size_t pidx = ((size_t)(b * HH + h)) * TT + i;
    float m0v = pm[pidx], m1v = pm[pidx + NHEADS * TT];
    float l0 = pl[pidx],  l1 = pl[pidx + NHEADS * TT];
    float M = fmaxf(m0v, m1v);
    float w0 = exp2f((m0v - M) * SCLOG2), w1 = exp2f((m1v - M) * SCLOG2);
    float p0 = bf2f(po[pidx * DH + d]);
    float p1 = bf2f(po[(size_t)NHEADS * TT * DH + pidx * DH + d]);
    float att = (p0 * w0 + p1 * w1) / (l0 * w0 + l1 * w1);
    v[p] = bf2f(xlnb[(size_t)r * CC + c]) + att;
  }
  float s = wred_sum(v[0] + v[1] + v[2]);
  __shared__ float red[4];
  if((t & 63) == 0) red[t >> 6] = s;
  __syncthreads();
  float mu = (red[0] + red[1] + red[2] + red[3]) * (1.0f / CC);
  float d0 = v[0] - mu, d1 = v[1] - mu, d2 = v[2] - mu;
  float q = wred_sum(d0 * d0 + d1 * d1 + d2 * d2);
  __shared__ float red2[4];
  if((t & 63) == 0) red2[t >> 6] = q;
  __syncthreads();
  float var = (red2[0] + red2[1] + red2[2] + red2[3]) * (1.0f / CC);
  float rinv = rsqrtf(var + 1e-3f);
  size_t base = (size_t)r * CC;
  x1[base + t] = v[0]; x1[base + t + 256] = v[1]; x1[base + t + 512] = v[2];
  hln2[base + t]       = f2bf(d0 * rinv * gm[t]       + bt[t]);
  hln2[base + t + 256] = f2bf(d1 * rinv * gm[t + 256] + bt[t + 256]);
  hln2[base + t + 512] = f2bf(d2 * rinv * gm[t + 512] + bt[t + 512]);
}

// ---------------- host launcher ----------------
extern "C" void kernel_launch(void* const* d_in, const int* in_sizes, int n_in,
                              void* d_out, int out_size, void* d_ws, size_t ws_size,
                              hipStream_t stream){
  const float* x    = (const float*)d_in[0];
  const float* ln1g = (const float*)d_in[1];
  const float* ln1b = (const float*)d_in[2];
  const float* Wq   = (const float*)d_in[3];
  const float* bq   = (const float*)d_in[4];
  const float* Wk   = (const float*)d_in[5];
  const float* bk   = (const float*)d_in[6];
  const float* Wv   = (const float*)d_in[7];
  const float* bv   = (const float*)d_in[8];
  const float* ln2g = (const float*)d_in[9];
  const float* ln2b = (const float*)d_in[10];
  const float* W1   = (const float*)d_in[11];
  const float* b1   = (const float*)d_in[12];
  const float* W2   = (const float*)d_in[13];
  const float* b2   = (const float*)d_in[14];

  char* ws = (char*)d_ws;
  unsigned short* po   = (unsigned short*)(ws + 0);         // 12582912 (2 splits x 24x2048x64 bf16)
  unsigned short* xlnb = (unsigned short*)(ws + 12582912);  // 6291456
  float*          x1   = (float*)(ws + 18874368);           // 12582912
  unsigned short* hln2 = (unsigned short*)(ws + 31457280);  // 6291456
  unsigned short* wqkv = (unsigned short*)(ws + 37748736);  // 3538944
  float*          bqkv = (float*)(ws + 41287680);           // 9216
  unsigned short* w1t  = (unsigned short*)(ws + 41296896);  // 4718592
  unsigned short* w2t  = (unsigned short*)(ws + 46015488);  // 4718592
  unsigned short* qkv  = (unsigned short*)(ws + 50734080);  // 18874368 (v third unused)
  unsigned short* vt   = (unsigned short*)(ws + 69608448);  // 6291456
  float*          pl   = (float*)(ws + 75899904);           // 393216
  float*          pm   = (float*)(ws + 76293120);           // 393216
  unsigned short* mlp1 = (unsigned short*)(ws + 50734080);  // aliases qkv+vt (dead by then)

  prep_ln_kernel<<<dim3(6345 + NROWS), 256, 0, stream>>>(Wq, Wk, Wv, W1, W2, bq, bk, bv,
                                                         x, ln1g, ln1b,
                                                         wqkv, w1t, w2t, bqkv, xlnb);

  gemm_bt<3, 128, 32><<<dim3(18, 32), 256, 0, stream>>>(xlnb, wqkv, bqkv, nullptr, qkv, vt, NROWS, 3 * CC, CC);

  attn_kernel<<<dim3(1536), 256, 0, stream>>>(qkv, vt, po, pl, pm);

  combine_ln2<<<dim3(NROWS), 256, 0, stream>>>(po, pl, pm, xlnb, ln2g, ln2b, x1, hln2);

  gemm_bt<1, 128, 32><<<dim3(24, 32), 256, 0, stream>>>(hln2, w1t, b1, nullptr, mlp1, nullptr, NROWS, 4 * CC, CC);

  gemm_bt<2, 64, 64><<<dim3(12, 64), 256, 0, stream>>>(mlp1, w2t, b2, x1, d_out, nullptr, NROWS, CC, 4 * CC);

  (void)in_sizes; (void)n_in; (void)out_size; (void)ws_size;
}